// Round 8
// baseline (235.252 us; speedup 1.0000x reference)
//
#include <hip/hip_runtime.h>
#include <math.h>

#define GENES 20000
#define LEVEL 10000
#define STEPS 7
#define DEG   16
#define EPSZ  (LEVEL * DEG)
#define CCOLS 32             // batch columns per chunk
#define NCHUNK 8             // chunks; pinned to XCD via bid%8 (perf only, not correctness)
#define BPC   128            // blocks per chunk
#define NBLK  (BPC * NCHUNK) // 1024 blocks, 4/CU co-resident via launch_bounds
#define NDG   313            // dest groups of 32 (ceil(10000/32))
#define NGT   625            // gene tiles of 32 (20000/32)

typedef unsigned short bf4 __attribute__((ext_vector_type(4)));

__device__ inline float bf2f(unsigned short u) {
    union { unsigned u; float f; } c; c.u = ((unsigned)u) << 16; return c.f;
}
__device__ inline unsigned short f2bf(float x) {     // round-to-nearest-even
    union { float f; unsigned u; } c; c.f = x;
    return (unsigned short)((c.u + 0x7fffu + ((c.u >> 16) & 1u)) >> 16);
}

// write-through stores (sc1): data reaches the device coherence point, so any
// consumer whose caches never held these (fresh) addresses reads fresh data.
__device__ inline void st8_wt(unsigned short* p, bf4 v) {
    union { bf4 v; unsigned long long u; } c; c.v = v;
    __hip_atomic_store(reinterpret_cast<unsigned long long*>(p), c.u,
                       __ATOMIC_RELAXED, __HIP_MEMORY_SCOPE_AGENT);
}
__device__ inline void st2_wt(unsigned short* p, unsigned short v) {
    __hip_atomic_store(p, v, __ATOMIC_RELAXED, __HIP_MEMORY_SCOPE_AGENT);
}
__device__ inline void st4_wt(float* p, float v) {
    __hip_atomic_store(p, v, __ATOMIC_RELAXED, __HIP_MEMORY_SCOPE_AGENT);
}

// per-chunk monotonic barrier: NO fences (no L2 wb/inv). Release = vmcnt drain
// before the relaxed agent atomic; visibility = sc1 stores + fresh buffers.
__device__ inline void chunk_barrier(int* cnt, int target) {
    __syncthreads();                               // drains vmcnt/lgkmcnt, HW+compiler barrier
    asm volatile("s_waitcnt vmcnt(0)" ::: "memory");
    if (threadIdx.x == 0) {
        __hip_atomic_fetch_add(cnt, 1, __ATOMIC_RELAXED, __HIP_MEMORY_SCOPE_AGENT);
        while (__hip_atomic_load(cnt, __ATOMIC_RELAXED, __HIP_MEMORY_SCOPE_AGENT) < target)
            __builtin_amdgcn_s_sleep(1);
    }
    __syncthreads();
}

__global__ __launch_bounds__(256, 4) void fused_k(
        const float* __restrict__ X,
        const float* __restrict__ edge_weight,
        const float* __restrict__ node_bias,
        const float* __restrict__ head_W,
        const float* __restrict__ head_b,
        const int*   __restrict__ gene_map,
        const int*   __restrict__ src,
        const int*   __restrict__ dst_unique,
        unsigned short* __restrict__ XT,   // [8][20000][32] bf16
        unsigned short* __restrict__ P0,   // 7 planes, each [8][10000][32] bf16
        float* __restrict__ part,          // [8][128][64]
        int*   __restrict__ cnt,           // [8][32] ints (128B-padded per chunk)
        float* __restrict__ out) {
    const int bid   = blockIdx.x;
    const int chunk = bid & 7;
    const int cb    = bid >> 3;            // 0..127 within chunk
    const int tid   = threadIdx.x;
    int* mycnt = cnt + chunk * 32;

    unsigned short* XTp = XT + (size_t)chunk * GENES * CCOLS;

    __shared__ float tile[32][33];
    __shared__ float red[4][8][8];

    // ---------------- phase 0: transpose my chunk's 32 batch rows ----------------
    {
        const int lo = tid & 31, r = tid >> 5;       // r = 0..7
        for (int gt = cb; gt < NGT; gt += BPC) {
            const int g0 = gt * 32;
#pragma unroll
            for (int j = 0; j < 4; ++j) {
                const int b = r + j * 8;             // batch row within chunk
                tile[b][lo] = X[(size_t)(chunk * CCOLS + b) * GENES + g0 + lo];
            }
            __syncthreads();
#pragma unroll
            for (int j = 0; j < 4; ++j) {
                const int gr   = r + j * 8;          // gene row within tile
                const int node = gene_map[g0 + gr];
                st2_wt(XTp + (size_t)node * CCOLS + lo, f2bf(tile[lo][gr]));
            }
            __syncthreads();
        }
    }
    int target = BPC;
    chunk_barrier(mycnt, target);

    const int wave = tid >> 6, lane = tid & 63;
    const int g    = lane >> 3;                      // dest slot within wave (0..7)
    const int colh = (lane & 7) * 4;                 // 4 bf16 cols of this chunk

#define GATHER_BODY(prevp, sbase)                                                           \
    const int be = dest * DEG;                                                              \
    const int4   s0 = *reinterpret_cast<const int4*>  (src_k + be);                         \
    const int4   s1 = *reinterpret_cast<const int4*>  (src_k + be + 4);                     \
    const int4   s2 = *reinterpret_cast<const int4*>  (src_k + be + 8);                     \
    const int4   s3 = *reinterpret_cast<const int4*>  (src_k + be + 12);                    \
    const float4 w0 = *reinterpret_cast<const float4*>(w_k + be);                           \
    const float4 w1 = *reinterpret_cast<const float4*>(w_k + be + 4);                       \
    const float4 w2 = *reinterpret_cast<const float4*>(w_k + be + 8);                       \
    const float4 w3 = *reinterpret_cast<const float4*>(w_k + be + 12);                      \
    float a0 = 0.f, a1 = 0.f, a2 = 0.f, a3 = 0.f;                                           \
    { _ACC(s0.x, w0.x) _ACC(s0.y, w0.y) _ACC(s0.z, w0.z) _ACC(s0.w, w0.w)                   \
      _ACC(s1.x, w1.x) _ACC(s1.y, w1.y) _ACC(s1.z, w1.z) _ACC(s1.w, w1.w)                   \
      _ACC(s2.x, w2.x) _ACC(s2.y, w2.y) _ACC(s2.z, w2.z) _ACC(s2.w, w2.w)                   \
      _ACC(s3.x, w3.x) _ACC(s3.y, w3.y) _ACC(s3.z, w3.z) _ACC(s3.w, w3.w) }

#define _ACC(sv, wv) { const int idx = (sv) - src_base;                                     \
    const bf4 v = *reinterpret_cast<const bf4*>(prev + (size_t)idx * CCOLS + colh);         \
    a0 = fmaf(bf2f(v[0]), (wv), a0); a1 = fmaf(bf2f(v[1]), (wv), a1);                       \
    a2 = fmaf(bf2f(v[2]), (wv), a2); a3 = fmaf(bf2f(v[3]), (wv), a3); }

    // ---------------- levels 1..6 (k = 0..5) ----------------
    for (int k = 0; k < STEPS - 1; ++k) {
        const unsigned short* prev = (k == 0) ? XTp
            : P0 + ((size_t)(k - 1) * NCHUNK + chunk) * LEVEL * CCOLS;
        unsigned short* curp = P0 + ((size_t)k * NCHUNK + chunk) * LEVEL * CCOLS;
        const int src_base = (k == 0) ? 0 : GENES + (k - 1) * LEVEL;
        const int*   src_k  = src         + k * EPSZ;
        const float* w_k    = edge_weight + k * EPSZ;
        const int*   dstu_k = dst_unique  + k * LEVEL;

        for (int dg = cb; dg < NDG; dg += BPC) {
            const int dest = dg * 32 + wave * 8 + g;
            if (dest < LEVEL) {
                GATHER_BODY(prev, src_base)
                const float bz = node_bias[dstu_k[dest]];
                bf4 o;
                o[0] = f2bf(tanhf(a0 + bz));
                o[1] = f2bf(tanhf(a1 + bz));
                o[2] = f2bf(tanhf(a2 + bz));
                o[3] = f2bf(tanhf(a3 + bz));
                st8_wt(curp + (size_t)dest * CCOLS + colh, o);
            }
        }
        target += BPC;
        chunk_barrier(mycnt, target);
    }

    // ---------------- level 7 fused with head partial (k = 6) ----------------
    {
        const int k = STEPS - 1;
        const unsigned short* prev = P0 + ((size_t)(k - 1) * NCHUNK + chunk) * LEVEL * CCOLS;
        const int src_base = GENES + (k - 1) * LEVEL;
        const int*   src_k  = src         + k * EPSZ;
        const float* w_k    = edge_weight + k * EPSZ;
        const int*   dstu_k = dst_unique  + k * LEVEL;

        float h0 = 0.f, h1 = 0.f, h2 = 0.f, h3 = 0.f, h4 = 0.f, h5 = 0.f, h6 = 0.f, h7 = 0.f;
        for (int dg = cb; dg < NDG; dg += BPC) {
            const int dest = dg * 32 + wave * 8 + g;
            if (dest < LEVEL) {
                GATHER_BODY(prev, src_base)
                const float bz = node_bias[dstu_k[dest]];
                const float o0 = tanhf(a0 + bz);
                const float o1 = tanhf(a1 + bz);
                const float o2 = tanhf(a2 + bz);
                const float o3 = tanhf(a3 + bz);
                const float2 wv = *reinterpret_cast<const float2*>(head_W + dest * 2);
                h0 = fmaf(o0, wv.x, h0); h1 = fmaf(o0, wv.y, h1);
                h2 = fmaf(o1, wv.x, h2); h3 = fmaf(o1, wv.y, h3);
                h4 = fmaf(o2, wv.x, h4); h5 = fmaf(o2, wv.y, h5);
                h6 = fmaf(o3, wv.x, h6); h7 = fmaf(o3, wv.y, h7);
            }
        }
#pragma unroll
        for (int m = 8; m < 64; m <<= 1) {
            h0 += __shfl_xor(h0, m); h1 += __shfl_xor(h1, m);
            h2 += __shfl_xor(h2, m); h3 += __shfl_xor(h3, m);
            h4 += __shfl_xor(h4, m); h5 += __shfl_xor(h5, m);
            h6 += __shfl_xor(h6, m); h7 += __shfl_xor(h7, m);
        }
        if (lane < 8) {
            red[wave][lane][0] = h0; red[wave][lane][1] = h1;
            red[wave][lane][2] = h2; red[wave][lane][3] = h3;
            red[wave][lane][4] = h4; red[wave][lane][5] = h5;
            red[wave][lane][6] = h6; red[wave][lane][7] = h7;
        }
        __syncthreads();
        if (tid < 64) {
            const int l8 = tid >> 3, v = tid & 7;
            const float s = red[0][l8][v] + red[1][l8][v] + red[2][l8][v] + red[3][l8][v];
            st4_wt(part + ((size_t)chunk * BPC + cb) * 64 + tid, s);
        }
    }
    target += BPC;
    chunk_barrier(mycnt, target);

    // ---------------- head final: block cb==0 of each chunk ----------------
    if (cb == 0 && tid < 64) {
        float acc = head_b[tid & 1];
        for (int q = 0; q < BPC; ++q)
            acc += part[((size_t)chunk * BPC + q) * 64 + tid];
        out[chunk * 64 + tid] = acc;       // == (chunk*32 + col)*2 + c
    }
#undef _ACC
#undef GATHER_BODY
}

// ---------------------------------------------------------------------------
extern "C" void kernel_launch(void* const* d_in, const int* in_sizes, int n_in,
                              void* d_out, int out_size, void* d_ws, size_t ws_size,
                              hipStream_t stream) {
    const float* X           = (const float*)d_in[0];
    const float* edge_weight = (const float*)d_in[1];
    const float* node_bias   = (const float*)d_in[2];
    const float* head_W      = (const float*)d_in[3];
    const float* head_b      = (const float*)d_in[4];
    const int*   gene_map    = (const int*)  d_in[5];
    const int*   src         = (const int*)  d_in[6];
    /* d_in[7] = dst_pos: structurally repeat(arange(LEVEL),DEG) — encoded in layout */
    const int*   dst_unique  = (const int*)  d_in[8];
    /* d_in[9] = eid: structurally arange(E).reshape(STEPS,EPS) — weights contiguous */
    /* d_in[10] = root_ids: structurally dst_unique[-1] — head fused into level 7 */
    float* out = (float*)d_out;

    // workspace layout (bytes); ws is 256 MiB (poison-fill WRITE_SIZE showed 268 MB)
    char* ws = (char*)d_ws;
    unsigned short* XT   = (unsigned short*)(ws);              // 8*20000*32*2 = 10,240,000
    unsigned short* P0   = (unsigned short*)(ws + 10240000);   // 7 * 8*10000*32*2 = 35,840,000
    float*          part = (float*)         (ws + 46080000);   // 8*128*64*4 = 262,144
    int*            cnt  = (int*)           (ws + 46342144);   // 8*32*4 = 1,024

    hipMemsetAsync(cnt, 0, NCHUNK * 32 * sizeof(int), stream); // captured; re-zeroed per replay

    fused_k<<<NBLK, 256, 0, stream>>>(X, edge_weight, node_bias, head_W, head_b,
                                      gene_map, src, dst_unique,
                                      XT, P0, part, cnt, out);
    (void)in_sizes; (void)n_in; (void)out_size; (void)ws_size;
}

// Round 9
// 93.476 us; speedup vs baseline: 2.5167x; 2.5167x over previous
//
#include <hip/hip_runtime.h>
#include <math.h>

#define GENES 20000
#define LEVEL 10000
#define STEPS 7
#define DEG   16
#define EPSZ  (LEVEL * DEG)
#define CCOLS 32             // batch columns per chunk
#define NCHUNK 8             // chunks == XCDs; chunk pinned to XCD via linear bid % 8
#define NDG   313            // dest groups of 32 (ceil(10000/32))
#define SBLK  157            // step blocks per chunk (64 dests each; 157*64 = 10048)
#define NGT   625            // gene tiles (20000/32)

typedef unsigned short bf4 __attribute__((ext_vector_type(4)));
typedef unsigned short bf8 __attribute__((ext_vector_type(8)));

__device__ inline float bf2f(unsigned short u) {
    union { unsigned u; float f; } c; c.u = ((unsigned)u) << 16; return c.f;
}
__device__ inline unsigned short f2bf(float x) {     // round-to-nearest-even
    union { float f; unsigned u; } c; c.f = x;
    return (unsigned short)((c.u + 0x7fffu + ((c.u >> 16) & 1u)) >> 16);
}

// ---------------------------------------------------------------------------
// Transpose X[b][g] (256 x 20000, fp32) -> 8 chunk planes XT[c][node][32] (bf16)
// grid (8, 157): blockIdx.x == chunk -> XCD pinning; 4 gene tiles per block
// ---------------------------------------------------------------------------
__global__ __launch_bounds__(256) void transpose_k(const float* __restrict__ X,
                                                   const int*   __restrict__ gene_map,
                                                   unsigned short* __restrict__ XT) {
    __shared__ float tile[32][33];
    const int chunk = blockIdx.x;                 // 0..7
    const int lo = threadIdx.x & 31, r = threadIdx.x >> 5;   // r = 0..7
    unsigned short* XTp = XT + (size_t)chunk * GENES * CCOLS;
    for (int i = 0; i < 4; ++i) {
        const int gt = blockIdx.y * 4 + i;
        if (gt >= NGT) break;
        const int g0 = gt * 32;
        if (i) __syncthreads();                   // protect tile reuse
#pragma unroll
        for (int j = 0; j < 4; ++j) {
            const int b = r + j * 8;              // batch row within chunk
            tile[b][lo] = X[(size_t)(chunk * CCOLS + b) * GENES + g0 + lo];
        }
        __syncthreads();
#pragma unroll
        for (int j = 0; j < 4; ++j) {
            const int gr   = r + j * 8;           // gene row within tile
            const int node = gene_map[g0 + gr];
            XTp[(size_t)node * CCOLS + lo] = f2bf(tile[lo][gr]);
        }
    }
}

// ---------------------------------------------------------------------------
// One DAG level (k = 0..5). Wave = 16 dests x 4 lanes x 8 bf16 cols (16B/lane).
// Block = 4 waves = 64 dests; 157 blocks/chunk; chunk = bid%8 -> XCD.
// ---------------------------------------------------------------------------
__global__ __launch_bounds__(256) void step_k(const unsigned short* __restrict__ hprev,
                                              unsigned short*       __restrict__ hcur,
                                              const int*   __restrict__ src_k,
                                              const float* __restrict__ w_k,
                                              const float* __restrict__ node_bias,
                                              const int*   __restrict__ dstu_k,
                                              int src_base, int prev_rows) {
    const int bid   = blockIdx.x;
    const int chunk = bid & 7;                 // -> XCD
    const int cb    = bid >> 3;                // 0..156
    const int wave  = threadIdx.x >> 6;
    const int lane  = threadIdx.x & 63;
    const int q     = lane >> 2;               // dest slot within wave (0..15)
    const int c8    = (lane & 3) * 8;          // 8 bf16 cols of this chunk

    const int dest = cb * 64 + wave * 16 + q;
    if (dest >= LEVEL) return;

    const unsigned short* prev = hprev + (size_t)chunk * prev_rows * CCOLS;
    unsigned short*       curp = hcur + (size_t)chunk * LEVEL * CCOLS;

    const int be = dest * DEG;
    const int4   s0 = *reinterpret_cast<const int4*>  (src_k + be);
    const int4   s1 = *reinterpret_cast<const int4*>  (src_k + be + 4);
    const int4   s2 = *reinterpret_cast<const int4*>  (src_k + be + 8);
    const int4   s3 = *reinterpret_cast<const int4*>  (src_k + be + 12);
    const float4 w0 = *reinterpret_cast<const float4*>(w_k + be);
    const float4 w1 = *reinterpret_cast<const float4*>(w_k + be + 4);
    const float4 w2 = *reinterpret_cast<const float4*>(w_k + be + 8);
    const float4 w3 = *reinterpret_cast<const float4*>(w_k + be + 12);

    float a0 = 0.f, a1 = 0.f, a2 = 0.f, a3 = 0.f, a4 = 0.f, a5 = 0.f, a6 = 0.f, a7 = 0.f;
#define ACC(sv, wv) { const int idx = (sv) - src_base;                                      \
    const bf8 v = *reinterpret_cast<const bf8*>(prev + (size_t)idx * CCOLS + c8);           \
    a0 = fmaf(bf2f(v[0]), (wv), a0); a1 = fmaf(bf2f(v[1]), (wv), a1);                       \
    a2 = fmaf(bf2f(v[2]), (wv), a2); a3 = fmaf(bf2f(v[3]), (wv), a3);                       \
    a4 = fmaf(bf2f(v[4]), (wv), a4); a5 = fmaf(bf2f(v[5]), (wv), a5);                       \
    a6 = fmaf(bf2f(v[6]), (wv), a6); a7 = fmaf(bf2f(v[7]), (wv), a7); }
    ACC(s0.x, w0.x) ACC(s0.y, w0.y) ACC(s0.z, w0.z) ACC(s0.w, w0.w)
    ACC(s1.x, w1.x) ACC(s1.y, w1.y) ACC(s1.z, w1.z) ACC(s1.w, w1.w)
    ACC(s2.x, w2.x) ACC(s2.y, w2.y) ACC(s2.z, w2.z) ACC(s2.w, w2.w)
    ACC(s3.x, w3.x) ACC(s3.y, w3.y) ACC(s3.z, w3.z) ACC(s3.w, w3.w)
#undef ACC
    const float bz = node_bias[dstu_k[dest]];
    bf8 o;
    o[0] = f2bf(tanhf(a0 + bz));
    o[1] = f2bf(tanhf(a1 + bz));
    o[2] = f2bf(tanhf(a2 + bz));
    o[3] = f2bf(tanhf(a3 + bz));
    o[4] = f2bf(tanhf(a4 + bz));
    o[5] = f2bf(tanhf(a5 + bz));
    o[6] = f2bf(tanhf(a6 + bz));
    o[7] = f2bf(tanhf(a7 + bz));
    *reinterpret_cast<bf8*>(curp + (size_t)dest * CCOLS + c8) = o;
}

// ---------------------------------------------------------------------------
// Step 7 fused with head stage 1 (unchanged from round 7; proven).
// ---------------------------------------------------------------------------
__global__ __launch_bounds__(256) void step7_head_k(const unsigned short* __restrict__ hprev,
                                                    const int*   __restrict__ src_k,
                                                    const float* __restrict__ w_k,
                                                    const float* __restrict__ node_bias,
                                                    const int*   __restrict__ dstu_k,
                                                    const float* __restrict__ head_W, // [LEVEL][2]
                                                    float*       __restrict__ part,
                                                    int src_base) {
    const int bid   = blockIdx.x;
    const int chunk = bid & 7;
    const int cb    = bid >> 3;                // 0..156
    const int wave  = threadIdx.x >> 6;
    const int lane  = threadIdx.x & 63;
    const int g     = lane >> 3;
    const int colh  = (lane & 7) * 4;

    const unsigned short* prev = hprev + (size_t)chunk * LEVEL * CCOLS;

    float h0 = 0.f, h1 = 0.f, h2 = 0.f, h3 = 0.f, h4 = 0.f, h5 = 0.f, h6 = 0.f, h7 = 0.f;

#pragma unroll
    for (int jj = 0; jj < 2; ++jj) {
        const int dg = cb + jj * SBLK;
        if (dg >= NDG) continue;
        const int dest = dg * 32 + wave * 8 + g;
        if (dest >= LEVEL) continue;

        const int be = dest * DEG;
        const int4   s0 = *reinterpret_cast<const int4*>  (src_k + be);
        const int4   s1 = *reinterpret_cast<const int4*>  (src_k + be + 4);
        const int4   s2 = *reinterpret_cast<const int4*>  (src_k + be + 8);
        const int4   s3 = *reinterpret_cast<const int4*>  (src_k + be + 12);
        const float4 w0 = *reinterpret_cast<const float4*>(w_k + be);
        const float4 w1 = *reinterpret_cast<const float4*>(w_k + be + 4);
        const float4 w2 = *reinterpret_cast<const float4*>(w_k + be + 8);
        const float4 w3 = *reinterpret_cast<const float4*>(w_k + be + 12);

        float a0 = 0.f, a1 = 0.f, a2 = 0.f, a3 = 0.f;
#define ACC(sv, wv) { const int idx = (sv) - src_base;                                      \
    const bf4 v = *reinterpret_cast<const bf4*>(prev + (size_t)idx * CCOLS + colh);         \
    a0 = fmaf(bf2f(v[0]), (wv), a0); a1 = fmaf(bf2f(v[1]), (wv), a1);                       \
    a2 = fmaf(bf2f(v[2]), (wv), a2); a3 = fmaf(bf2f(v[3]), (wv), a3); }
        ACC(s0.x, w0.x) ACC(s0.y, w0.y) ACC(s0.z, w0.z) ACC(s0.w, w0.w)
        ACC(s1.x, w1.x) ACC(s1.y, w1.y) ACC(s1.z, w1.z) ACC(s1.w, w1.w)
        ACC(s2.x, w2.x) ACC(s2.y, w2.y) ACC(s2.z, w2.z) ACC(s2.w, w2.w)
        ACC(s3.x, w3.x) ACC(s3.y, w3.y) ACC(s3.z, w3.z) ACC(s3.w, w3.w)
#undef ACC
        const float bz = node_bias[dstu_k[dest]];
        const float o0 = tanhf(a0 + bz);
        const float o1 = tanhf(a1 + bz);
        const float o2 = tanhf(a2 + bz);
        const float o3 = tanhf(a3 + bz);
        const float2 wv = *reinterpret_cast<const float2*>(head_W + dest * 2);
        h0 = fmaf(o0, wv.x, h0); h1 = fmaf(o0, wv.y, h1);
        h2 = fmaf(o1, wv.x, h2); h3 = fmaf(o1, wv.y, h3);
        h4 = fmaf(o2, wv.x, h4); h5 = fmaf(o2, wv.y, h5);
        h6 = fmaf(o3, wv.x, h6); h7 = fmaf(o3, wv.y, h7);
    }

#pragma unroll
    for (int m = 8; m < 64; m <<= 1) {
        h0 += __shfl_xor(h0, m); h1 += __shfl_xor(h1, m);
        h2 += __shfl_xor(h2, m); h3 += __shfl_xor(h3, m);
        h4 += __shfl_xor(h4, m); h5 += __shfl_xor(h5, m);
        h6 += __shfl_xor(h6, m); h7 += __shfl_xor(h7, m);
    }
    __shared__ float red[4][8][8];
    if (lane < 8) {
        red[wave][lane][0] = h0; red[wave][lane][1] = h1;
        red[wave][lane][2] = h2; red[wave][lane][3] = h3;
        red[wave][lane][4] = h4; red[wave][lane][5] = h5;
        red[wave][lane][6] = h6; red[wave][lane][7] = h7;
    }
    __syncthreads();
    if (threadIdx.x < 64) {
        const int l8 = threadIdx.x >> 3, v = threadIdx.x & 7;
        const float s = red[0][l8][v] + red[1][l8][v] + red[2][l8][v] + red[3][l8][v];
        part[((size_t)chunk * SBLK + cb) * 64 + threadIdx.x] = s;
    }
}

// ---------------------------------------------------------------------------
// Head final: out[chunk*64 + t] = head_b[t&1] + sum_q part[(chunk*157+q)*64+t]
// ---------------------------------------------------------------------------
__global__ __launch_bounds__(64) void head_final_k(const float* __restrict__ part,
                                                   const float* __restrict__ head_b,
                                                   float*       __restrict__ out) {
    const int chunk = blockIdx.x;              // 8
    const int t     = threadIdx.x;             // 64
    float acc = head_b[t & 1];
    for (int q = 0; q < SBLK; ++q)
        acc += part[((size_t)chunk * SBLK + q) * 64 + t];
    out[chunk * 64 + t] = acc;
}

// ---------------------------------------------------------------------------
extern "C" void kernel_launch(void* const* d_in, const int* in_sizes, int n_in,
                              void* d_out, int out_size, void* d_ws, size_t ws_size,
                              hipStream_t stream) {
    const float* X           = (const float*)d_in[0];
    const float* edge_weight = (const float*)d_in[1];
    const float* node_bias   = (const float*)d_in[2];
    const float* head_W      = (const float*)d_in[3];
    const float* head_b      = (const float*)d_in[4];
    const int*   gene_map    = (const int*)  d_in[5];
    const int*   src         = (const int*)  d_in[6];
    /* d_in[7] = dst_pos: structurally repeat(arange(LEVEL),DEG) — encoded in layout */
    const int*   dst_unique  = (const int*)  d_in[8];
    /* d_in[9] = eid: structurally arange(E).reshape(STEPS,EPS) — weights contiguous */
    /* d_in[10] = root_ids: structurally dst_unique[-1] — head fused into step 7 */
    float* out = (float*)d_out;

    // workspace layout (bytes)
    char* ws = (char*)d_ws;
    unsigned short* XT   = (unsigned short*)(ws);              // 8*20000*32*2 = 10,240,000
    unsigned short* lvlA = (unsigned short*)(ws + 10240000);   // 8*10000*32*2 =  5,120,000
    unsigned short* lvlB = (unsigned short*)(ws + 15360000);   //                 5,120,000
    float*          part = (float*)         (ws + 20480000);   // 8*157*64*4   =    321,536

    // 1) transpose X into chunked bf16 node-major planes (chunk -> XCD pinned)
    transpose_k<<<dim3(NCHUNK, 157), 256, 0, stream>>>(X, gene_map, XT);

    // 2) levels 1..6, ping-pong level buffers, chunk -> XCD pinned
    unsigned short* bufs[2] = {lvlA, lvlB};
    for (int k = 0; k < STEPS - 1; ++k) {
        const unsigned short* hprev = (k == 0) ? XT : bufs[(k - 1) & 1];
        const int prevrows = (k == 0) ? GENES : LEVEL;
        const int srcbase  = (k == 0) ? 0 : GENES + (k - 1) * LEVEL;
        step_k<<<SBLK * NCHUNK, 256, 0, stream>>>(hprev, bufs[k & 1],
                                                  src + (size_t)k * EPSZ,
                                                  edge_weight + (size_t)k * EPSZ,
                                                  node_bias,
                                                  dst_unique + (size_t)k * LEVEL,
                                                  srcbase, prevrows);
    }

    // 3) level 7 fused with head partials (no plane store), then tiny final
    {
        const int k = STEPS - 1;                            // 6
        const unsigned short* hprev = bufs[(k - 1) & 1];    // lvlB
        const int srcbase = GENES + (k - 1) * LEVEL;
        step7_head_k<<<SBLK * NCHUNK, 256, 0, stream>>>(hprev,
                                                        src + (size_t)k * EPSZ,
                                                        edge_weight + (size_t)k * EPSZ,
                                                        node_bias,
                                                        dst_unique + (size_t)k * LEVEL,
                                                        head_W, part, srcbase);
        head_final_k<<<NCHUNK, 64, 0, stream>>>(part, head_b, out);
    }
    (void)in_sizes; (void)n_in; (void)out_size; (void)ws_size;
}

// Round 10
// 91.682 us; speedup vs baseline: 2.5660x; 1.0196x over previous
//
#include <hip/hip_runtime.h>
#include <math.h>

#define GENES 20000
#define LEVEL 10000
#define STEPS 7
#define DEG   16
#define EPSZ  (LEVEL * DEG)
#define CCOLS 32             // batch columns per chunk
#define NCHUNK 8             // chunks == XCDs; chunk pinned to XCD via linear bid % 8
#define SBLK  157            // step blocks per chunk (64 dests each; 157*64 = 10048)
#define NGT   625            // gene tiles (20000/32)
#define MSTRIDE 18           // LDS metadata stride (16 + 2 pad) -> distinct banks per dest

typedef unsigned short bf8 __attribute__((ext_vector_type(8)));

__device__ inline float bf2f(unsigned short u) {
    union { unsigned u; float f; } c; c.u = ((unsigned)u) << 16; return c.f;
}
__device__ inline unsigned short f2bf(float x) {     // round-to-nearest-even
    union { float f; unsigned u; } c; c.f = x;
    return (unsigned short)((c.u + 0x7fffu + ((c.u >> 16) & 1u)) >> 16);
}

// ---------------------------------------------------------------------------
// Transpose X[b][g] (256 x 20000, fp32) -> 8 chunk planes XT[c][node][32] (bf16)
// grid (8, 157): blockIdx.x == chunk -> XCD pinning; 4 gene tiles per block
// ---------------------------------------------------------------------------
__global__ __launch_bounds__(256) void transpose_k(const float* __restrict__ X,
                                                   const int*   __restrict__ gene_map,
                                                   unsigned short* __restrict__ XT) {
    __shared__ float tile[32][33];
    const int chunk = blockIdx.x;                 // 0..7
    const int lo = threadIdx.x & 31, r = threadIdx.x >> 5;   // r = 0..7
    unsigned short* XTp = XT + (size_t)chunk * GENES * CCOLS;
    for (int i = 0; i < 4; ++i) {
        const int gt = blockIdx.y * 4 + i;
        if (gt >= NGT) break;
        const int g0 = gt * 32;
        if (i) __syncthreads();                   // protect tile reuse
#pragma unroll
        for (int j = 0; j < 4; ++j) {
            const int b = r + j * 8;              // batch row within chunk
            tile[b][lo] = X[(size_t)(chunk * CCOLS + b) * GENES + g0 + lo];
        }
        __syncthreads();
#pragma unroll
        for (int j = 0; j < 4; ++j) {
            const int gr   = r + j * 8;           // gene row within tile
            const int node = gene_map[g0 + gr];
            XTp[(size_t)node * CCOLS + lo] = f2bf(tile[lo][gr]);
        }
    }
}

// ---------------------------------------------------------------------------
// One DAG level (k = 0..5). Block = 64 dests; metadata LDS-staged (coalesced
// 16B/thread loads), then wave = 16 dests x 4 lanes x 8 bf16 cols gathers.
// ---------------------------------------------------------------------------
__global__ __launch_bounds__(256) void step_k(const unsigned short* __restrict__ hprev,
                                              unsigned short*       __restrict__ hcur,
                                              const int*   __restrict__ src_k,
                                              const float* __restrict__ w_k,
                                              const float* __restrict__ node_bias,
                                              const int*   __restrict__ dstu_k,
                                              int src_base, int prev_rows) {
    const int bid   = blockIdx.x;
    const int chunk = bid & 7;                 // -> XCD
    const int cb    = bid >> 3;                // 0..156
    const int tid   = threadIdx.x;

    __shared__ int   s_src[64 * MSTRIDE];
    __shared__ float s_w  [64 * MSTRIDE];

    // stage this block's 64 dests' metadata: 2 coalesced 16B loads per thread
    {
        const int m4 = cb * 256 + tid;         // int4/float4 index
        if (m4 < EPSZ / 4) {
            const int4   sv = reinterpret_cast<const int4*>(src_k)[m4];
            const float4 wv = reinterpret_cast<const float4*>(w_k)[m4];
            const int j = tid >> 2, i = (tid & 3) * 4;
            *reinterpret_cast<int4*>  (&s_src[j * MSTRIDE + i]) = sv;
            *reinterpret_cast<float4*>(&s_w  [j * MSTRIDE + i]) = wv;
        }
    }
    __syncthreads();

    const int wave = tid >> 6, lane = tid & 63;
    const int q    = lane >> 2;                // dest slot within wave (0..15)
    const int c8   = (lane & 3) * 8;           // 8 bf16 cols of this chunk
    const int j    = wave * 16 + q;            // dest within block (0..63)
    const int dest = cb * 64 + j;
    if (dest >= LEVEL) return;

    const unsigned short* prev = hprev + (size_t)chunk * prev_rows * CCOLS;
    unsigned short*       curp = hcur + (size_t)chunk * LEVEL * CCOLS;

    const int4   s0 = *reinterpret_cast<const int4*>  (&s_src[j * MSTRIDE + 0]);
    const int4   s1 = *reinterpret_cast<const int4*>  (&s_src[j * MSTRIDE + 4]);
    const int4   s2 = *reinterpret_cast<const int4*>  (&s_src[j * MSTRIDE + 8]);
    const int4   s3 = *reinterpret_cast<const int4*>  (&s_src[j * MSTRIDE + 12]);
    const float4 w0 = *reinterpret_cast<const float4*>(&s_w  [j * MSTRIDE + 0]);
    const float4 w1 = *reinterpret_cast<const float4*>(&s_w  [j * MSTRIDE + 4]);
    const float4 w2 = *reinterpret_cast<const float4*>(&s_w  [j * MSTRIDE + 8]);
    const float4 w3 = *reinterpret_cast<const float4*>(&s_w  [j * MSTRIDE + 12]);

    float a0 = 0.f, a1 = 0.f, a2 = 0.f, a3 = 0.f, a4 = 0.f, a5 = 0.f, a6 = 0.f, a7 = 0.f;
#define ACC(sv, wv) { const int idx = (sv) - src_base;                                      \
    const bf8 v = *reinterpret_cast<const bf8*>(prev + (size_t)idx * CCOLS + c8);           \
    a0 = fmaf(bf2f(v[0]), (wv), a0); a1 = fmaf(bf2f(v[1]), (wv), a1);                       \
    a2 = fmaf(bf2f(v[2]), (wv), a2); a3 = fmaf(bf2f(v[3]), (wv), a3);                       \
    a4 = fmaf(bf2f(v[4]), (wv), a4); a5 = fmaf(bf2f(v[5]), (wv), a5);                       \
    a6 = fmaf(bf2f(v[6]), (wv), a6); a7 = fmaf(bf2f(v[7]), (wv), a7); }
    ACC(s0.x, w0.x) ACC(s0.y, w0.y) ACC(s0.z, w0.z) ACC(s0.w, w0.w)
    ACC(s1.x, w1.x) ACC(s1.y, w1.y) ACC(s1.z, w1.z) ACC(s1.w, w1.w)
    ACC(s2.x, w2.x) ACC(s2.y, w2.y) ACC(s2.z, w2.z) ACC(s2.w, w2.w)
    ACC(s3.x, w3.x) ACC(s3.y, w3.y) ACC(s3.z, w3.z) ACC(s3.w, w3.w)
#undef ACC
    const float bz = node_bias[dstu_k[dest]];
    bf8 o;
    o[0] = f2bf(tanhf(a0 + bz));
    o[1] = f2bf(tanhf(a1 + bz));
    o[2] = f2bf(tanhf(a2 + bz));
    o[3] = f2bf(tanhf(a3 + bz));
    o[4] = f2bf(tanhf(a4 + bz));
    o[5] = f2bf(tanhf(a5 + bz));
    o[6] = f2bf(tanhf(a6 + bz));
    o[7] = f2bf(tanhf(a7 + bz));
    *reinterpret_cast<bf8*>(curp + (size_t)dest * CCOLS + c8) = o;
}

// ---------------------------------------------------------------------------
// Step 7 fused with head stage 1. Phase A: same gather core as step_k, tanh
// outputs -> LDS tile (no plane store). Phase B: deterministic W-multiply +
// fixed-tree reduce -> per-block partials. root_ids == dst_unique[-1].
// ---------------------------------------------------------------------------
__global__ __launch_bounds__(256) void step7_head_k(const unsigned short* __restrict__ hprev,
                                                    const int*   __restrict__ src_k,
                                                    const float* __restrict__ w_k,
                                                    const float* __restrict__ node_bias,
                                                    const int*   __restrict__ dstu_k,
                                                    const float* __restrict__ head_W, // [LEVEL][2]
                                                    float*       __restrict__ part,
                                                    int src_base) {
    const int bid   = blockIdx.x;
    const int chunk = bid & 7;
    const int cb    = bid >> 3;                // 0..156
    const int tid   = threadIdx.x;

    __shared__ int   s_src[64 * MSTRIDE];
    __shared__ float s_w  [64 * MSTRIDE];
    __shared__ float o_tile[64][33];
    __shared__ float s_W2[64][2];
    __shared__ float red[8][64];

    // stage metadata (as step_k)
    {
        const int m4 = cb * 256 + tid;
        if (m4 < EPSZ / 4) {
            const int4   sv = reinterpret_cast<const int4*>(src_k)[m4];
            const float4 wv = reinterpret_cast<const float4*>(w_k)[m4];
            const int j = tid >> 2, i = (tid & 3) * 4;
            *reinterpret_cast<int4*>  (&s_src[j * MSTRIDE + i]) = sv;
            *reinterpret_cast<float4*>(&s_w  [j * MSTRIDE + i]) = wv;
        }
    }
    // stage head_W rows for this block's 64 dests (zero-fill past LEVEL)
    if (tid < 32) {
        const int f4 = cb * 32 + tid;          // float4 idx; head_W has LEVEL*2/4 = 5000
        float4 wv = make_float4(0.f, 0.f, 0.f, 0.f);
        if (f4 < (LEVEL * 2) / 4) wv = reinterpret_cast<const float4*>(head_W)[f4];
        s_W2[tid * 2 + 0][0] = wv.x; s_W2[tid * 2 + 0][1] = wv.y;
        s_W2[tid * 2 + 1][0] = wv.z; s_W2[tid * 2 + 1][1] = wv.w;
    }
    __syncthreads();

    const int wave = tid >> 6, lane = tid & 63;
    const int q    = lane >> 2;
    const int c8   = (lane & 3) * 8;
    const int j    = wave * 16 + q;
    const int dest = cb * 64 + j;

    const unsigned short* prev = hprev + (size_t)chunk * LEVEL * CCOLS;

    float o0 = 0.f, o1 = 0.f, o2 = 0.f, o3 = 0.f, o4 = 0.f, o5 = 0.f, o6 = 0.f, o7 = 0.f;
    if (dest < LEVEL) {
        const int4   s0 = *reinterpret_cast<const int4*>  (&s_src[j * MSTRIDE + 0]);
        const int4   s1 = *reinterpret_cast<const int4*>  (&s_src[j * MSTRIDE + 4]);
        const int4   s2 = *reinterpret_cast<const int4*>  (&s_src[j * MSTRIDE + 8]);
        const int4   s3 = *reinterpret_cast<const int4*>  (&s_src[j * MSTRIDE + 12]);
        const float4 w0 = *reinterpret_cast<const float4*>(&s_w  [j * MSTRIDE + 0]);
        const float4 w1 = *reinterpret_cast<const float4*>(&s_w  [j * MSTRIDE + 4]);
        const float4 w2 = *reinterpret_cast<const float4*>(&s_w  [j * MSTRIDE + 8]);
        const float4 w3 = *reinterpret_cast<const float4*>(&s_w  [j * MSTRIDE + 12]);

        float a0 = 0.f, a1 = 0.f, a2 = 0.f, a3 = 0.f, a4 = 0.f, a5 = 0.f, a6 = 0.f, a7 = 0.f;
#define ACC(sv, wv) { const int idx = (sv) - src_base;                                      \
    const bf8 v = *reinterpret_cast<const bf8*>(prev + (size_t)idx * CCOLS + c8);           \
    a0 = fmaf(bf2f(v[0]), (wv), a0); a1 = fmaf(bf2f(v[1]), (wv), a1);                       \
    a2 = fmaf(bf2f(v[2]), (wv), a2); a3 = fmaf(bf2f(v[3]), (wv), a3);                       \
    a4 = fmaf(bf2f(v[4]), (wv), a4); a5 = fmaf(bf2f(v[5]), (wv), a5);                       \
    a6 = fmaf(bf2f(v[6]), (wv), a6); a7 = fmaf(bf2f(v[7]), (wv), a7); }
        ACC(s0.x, w0.x) ACC(s0.y, w0.y) ACC(s0.z, w0.z) ACC(s0.w, w0.w)
        ACC(s1.x, w1.x) ACC(s1.y, w1.y) ACC(s1.z, w1.z) ACC(s1.w, w1.w)
        ACC(s2.x, w2.x) ACC(s2.y, w2.y) ACC(s2.z, w2.z) ACC(s2.w, w2.w)
        ACC(s3.x, w3.x) ACC(s3.y, w3.y) ACC(s3.z, w3.z) ACC(s3.w, w3.w)
#undef ACC
        const float bz = node_bias[dstu_k[dest]];
        o0 = tanhf(a0 + bz); o1 = tanhf(a1 + bz); o2 = tanhf(a2 + bz); o3 = tanhf(a3 + bz);
        o4 = tanhf(a4 + bz); o5 = tanhf(a5 + bz); o6 = tanhf(a6 + bz); o7 = tanhf(a7 + bz);
    }
    o_tile[j][c8 + 0] = o0; o_tile[j][c8 + 1] = o1;
    o_tile[j][c8 + 2] = o2; o_tile[j][c8 + 3] = o3;
    o_tile[j][c8 + 4] = o4; o_tile[j][c8 + 5] = o5;
    o_tile[j][c8 + 6] = o6; o_tile[j][c8 + 7] = o7;
    __syncthreads();

    // phase B: col = tid&31, slot = tid>>5 sums its 8 dests (fixed order)
    {
        const int col = tid & 31, slot = tid >> 5;
        float a0 = 0.f, a1 = 0.f;
#pragma unroll
        for (int e = 0; e < 8; ++e) {
            const int jj = slot * 8 + e;
            const float v = o_tile[jj][col];
            a0 = fmaf(v, s_W2[jj][0], a0);
            a1 = fmaf(v, s_W2[jj][1], a1);
        }
        red[slot][col * 2 + 0] = a0;
        red[slot][col * 2 + 1] = a1;
    }
    __syncthreads();
    if (tid < 64) {
        float s = 0.f;
#pragma unroll
        for (int p = 0; p < 8; ++p) s += red[p][tid];
        part[((size_t)chunk * SBLK + cb) * 64 + tid] = s;
    }
}

// ---------------------------------------------------------------------------
// Head final: out[chunk*64 + t] = head_b[t&1] + sum_q part[(chunk*157+q)*64+t]
// ---------------------------------------------------------------------------
__global__ __launch_bounds__(64) void head_final_k(const float* __restrict__ part,
                                                   const float* __restrict__ head_b,
                                                   float*       __restrict__ out) {
    const int chunk = blockIdx.x;              // 8
    const int t     = threadIdx.x;             // 64
    float acc = head_b[t & 1];
    for (int q = 0; q < SBLK; ++q)
        acc += part[((size_t)chunk * SBLK + q) * 64 + t];
    out[chunk * 64 + t] = acc;
}

// ---------------------------------------------------------------------------
extern "C" void kernel_launch(void* const* d_in, const int* in_sizes, int n_in,
                              void* d_out, int out_size, void* d_ws, size_t ws_size,
                              hipStream_t stream) {
    const float* X           = (const float*)d_in[0];
    const float* edge_weight = (const float*)d_in[1];
    const float* node_bias   = (const float*)d_in[2];
    const float* head_W      = (const float*)d_in[3];
    const float* head_b      = (const float*)d_in[4];
    const int*   gene_map    = (const int*)  d_in[5];
    const int*   src         = (const int*)  d_in[6];
    /* d_in[7] = dst_pos: structurally repeat(arange(LEVEL),DEG) — encoded in layout */
    const int*   dst_unique  = (const int*)  d_in[8];
    /* d_in[9] = eid: structurally arange(E).reshape(STEPS,EPS) — weights contiguous */
    /* d_in[10] = root_ids: structurally dst_unique[-1] — head fused into step 7 */
    float* out = (float*)d_out;

    // workspace layout (bytes)
    char* ws = (char*)d_ws;
    unsigned short* XT   = (unsigned short*)(ws);              // 8*20000*32*2 = 10,240,000
    unsigned short* lvlA = (unsigned short*)(ws + 10240000);   // 8*10000*32*2 =  5,120,000
    unsigned short* lvlB = (unsigned short*)(ws + 15360000);   //                 5,120,000
    float*          part = (float*)         (ws + 20480000);   // 8*157*64*4   =    321,536

    // 1) transpose X into chunked bf16 node-major planes (chunk -> XCD pinned)
    transpose_k<<<dim3(NCHUNK, 157), 256, 0, stream>>>(X, gene_map, XT);

    // 2) levels 1..6, ping-pong level buffers, chunk -> XCD pinned
    unsigned short* bufs[2] = {lvlA, lvlB};
    for (int k = 0; k < STEPS - 1; ++k) {
        const unsigned short* hprev = (k == 0) ? XT : bufs[(k - 1) & 1];
        const int prevrows = (k == 0) ? GENES : LEVEL;
        const int srcbase  = (k == 0) ? 0 : GENES + (k - 1) * LEVEL;
        step_k<<<SBLK * NCHUNK, 256, 0, stream>>>(hprev, bufs[k & 1],
                                                  src + (size_t)k * EPSZ,
                                                  edge_weight + (size_t)k * EPSZ,
                                                  node_bias,
                                                  dst_unique + (size_t)k * LEVEL,
                                                  srcbase, prevrows);
    }

    // 3) level 7 fused with head partials (no plane store), then tiny final
    {
        const int k = STEPS - 1;                            // 6
        const unsigned short* hprev = bufs[(k - 1) & 1];    // lvlB
        const int srcbase = GENES + (k - 1) * LEVEL;
        step7_head_k<<<SBLK * NCHUNK, 256, 0, stream>>>(hprev,
                                                        src + (size_t)k * EPSZ,
                                                        edge_weight + (size_t)k * EPSZ,
                                                        node_bias,
                                                        dst_unique + (size_t)k * LEVEL,
                                                        head_W, part, srcbase);
        head_final_k<<<NCHUNK, 64, 0, stream>>>(part, head_b, out);
    }
    (void)in_sizes; (void)n_in; (void)out_size; (void)ws_size;
}

// Round 11
// 91.307 us; speedup vs baseline: 2.5765x; 1.0041x over previous
//
#include <hip/hip_runtime.h>
#include <math.h>

#define GENES 20000
#define LEVEL 10000
#define STEPS 7
#define DEG   16
#define EPSZ  (LEVEL * DEG)
#define CCOLS 32             // batch columns per chunk
#define NCHUNK 8             // chunks == XCDs; chunk pinned to XCD via linear bid % 8
#define SBLK  157            // step7 blocks per chunk (64 dests each)
#define DBLK  313            // step blocks per chunk (32 dests each; 313*32 = 10016)
#define NGT   625            // gene tiles (20000/32)
#define MSTRIDE 18           // LDS metadata stride (16 + 2 pad)

typedef unsigned short bf8 __attribute__((ext_vector_type(8)));

__device__ inline float bf2f(unsigned short u) {
    union { unsigned u; float f; } c; c.u = ((unsigned)u) << 16; return c.f;
}
__device__ inline unsigned short f2bf(float x) {     // round-to-nearest-even
    union { float f; unsigned u; } c; c.f = x;
    return (unsigned short)((c.u + 0x7fffu + ((c.u >> 16) & 1u)) >> 16);
}

// ---------------------------------------------------------------------------
// Transpose X[b][g] (256 x 20000, fp32) -> 8 chunk planes XT[c][node][32] (bf16)
// grid (8, 157): blockIdx.x == chunk -> XCD pinning; 4 gene tiles per block.
// Global loads are float4; LDS tile writes scalar into stride-33 (conflict-free
// transposed read).
// ---------------------------------------------------------------------------
__global__ __launch_bounds__(256) void transpose_k(const float* __restrict__ X,
                                                   const int*   __restrict__ gene_map,
                                                   unsigned short* __restrict__ XT) {
    __shared__ float tile[32][33];
    const int chunk = blockIdx.x;                 // 0..7
    const int l4  = threadIdx.x & 7;              // float4 slot within gene row
    const int r8  = threadIdx.x >> 3;             // batch row within chunk (0..31)
    const int lo  = threadIdx.x & 31;             // batch col for store phase
    const int gr8 = threadIdx.x >> 5;             // gene row base (0..7)
    unsigned short* XTp = XT + (size_t)chunk * GENES * CCOLS;
    for (int i = 0; i < 4; ++i) {
        const int gt = blockIdx.y * 4 + i;
        if (gt >= NGT) break;
        const int g0 = gt * 32;
        if (i) __syncthreads();                   // protect tile reuse
        const float4 xv = *reinterpret_cast<const float4*>(
            X + (size_t)(chunk * CCOLS + r8) * GENES + g0 + l4 * 4);
        tile[r8][l4 * 4 + 0] = xv.x;
        tile[r8][l4 * 4 + 1] = xv.y;
        tile[r8][l4 * 4 + 2] = xv.z;
        tile[r8][l4 * 4 + 3] = xv.w;
        __syncthreads();
#pragma unroll
        for (int jj = 0; jj < 4; ++jj) {
            const int gr   = gr8 + jj * 8;        // gene row within tile
            const int node = gene_map[g0 + gr];
            XTp[(size_t)node * CCOLS + lo] = f2bf(tile[lo][gr]);
        }
    }
}

// ---------------------------------------------------------------------------
// One DAG level (k = 0..5). Dest = 8 lanes: 4 col-groups x 2 edge-halves.
// Wave = 8 dests; block = 32 dests; 313 blocks/chunk -> ~2x waves vs r10.
// All 8 gathers hoisted into registers before FMA (max MLP).
// ---------------------------------------------------------------------------
__global__ __launch_bounds__(256) void step_k(const unsigned short* __restrict__ hprev,
                                              unsigned short*       __restrict__ hcur,
                                              const int*   __restrict__ src_k,
                                              const float* __restrict__ w_k,
                                              const float* __restrict__ node_bias,
                                              const int*   __restrict__ dstu_k,
                                              int src_base, int prev_rows) {
    const int bid   = blockIdx.x;
    const int chunk = bid & 7;                 // -> XCD
    const int cb    = bid >> 3;                // 0..312
    const int tid   = threadIdx.x;

    __shared__ int   s_src[32 * MSTRIDE];
    __shared__ float s_w  [32 * MSTRIDE];

    // stage this block's 32 dests' metadata (512 ints + 512 floats)
    if (tid < 128) {
        const int m4 = cb * 128 + tid;
        if (m4 < EPSZ / 4) {
            const int4 sv = reinterpret_cast<const int4*>(src_k)[m4];
            const int j = tid >> 2, i = (tid & 3) * 4;
            *reinterpret_cast<int4*>(&s_src[j * MSTRIDE + i]) = sv;
        }
    } else {
        const int t  = tid - 128;
        const int m4 = cb * 128 + t;
        if (m4 < EPSZ / 4) {
            const float4 wv = reinterpret_cast<const float4*>(w_k)[m4];
            const int j = t >> 2, i = (t & 3) * 4;
            *reinterpret_cast<float4*>(&s_w[j * MSTRIDE + i]) = wv;
        }
    }
    __syncthreads();

    const int wave = tid >> 6, lane = tid & 63;
    const int c2 = lane & 3;                   // col group (8 bf16 cols)
    const int eh = (lane >> 2) & 1;            // edge half (0: e0-7, 1: e8-15)
    const int q  = lane >> 3;                  // dest slot within wave (0..7)
    const int j  = wave * 8 + q;               // dest within block (0..31)
    const int dest = cb * 32 + j;
    const int c8 = c2 * 8;

    if (dest < LEVEL) {
        const unsigned short* prev = hprev + (size_t)chunk * prev_rows * CCOLS;
        unsigned short*       curp = hcur + (size_t)chunk * LEVEL * CCOLS;

        const int mb = j * MSTRIDE + eh * 8;
        const int4   sA = *reinterpret_cast<const int4*>  (&s_src[mb]);
        const int4   sB = *reinterpret_cast<const int4*>  (&s_src[mb + 4]);
        const float4 wA = *reinterpret_cast<const float4*>(&s_w  [mb]);
        const float4 wB = *reinterpret_cast<const float4*>(&s_w  [mb + 4]);

        // hoist all 8 gathers (independent, max outstanding)
#define GL(sv) (*reinterpret_cast<const bf8*>(prev + (size_t)((sv) - src_base) * CCOLS + c8))
        const bf8 v0 = GL(sA.x);
        const bf8 v1 = GL(sA.y);
        const bf8 v2 = GL(sA.z);
        const bf8 v3 = GL(sA.w);
        const bf8 v4 = GL(sB.x);
        const bf8 v5 = GL(sB.y);
        const bf8 v6 = GL(sB.z);
        const bf8 v7 = GL(sB.w);
#undef GL

        float a0 = 0.f, a1 = 0.f, a2 = 0.f, a3 = 0.f, a4 = 0.f, a5 = 0.f, a6 = 0.f, a7 = 0.f;
#define FMA8(v, wv) { a0 = fmaf(bf2f((v)[0]), (wv), a0); a1 = fmaf(bf2f((v)[1]), (wv), a1);  \
                      a2 = fmaf(bf2f((v)[2]), (wv), a2); a3 = fmaf(bf2f((v)[3]), (wv), a3);  \
                      a4 = fmaf(bf2f((v)[4]), (wv), a4); a5 = fmaf(bf2f((v)[5]), (wv), a5);  \
                      a6 = fmaf(bf2f((v)[6]), (wv), a6); a7 = fmaf(bf2f((v)[7]), (wv), a7); }
        FMA8(v0, wA.x) FMA8(v1, wA.y) FMA8(v2, wA.z) FMA8(v3, wA.w)
        FMA8(v4, wB.x) FMA8(v5, wB.y) FMA8(v6, wB.z) FMA8(v7, wB.w)
#undef FMA8

        // combine the two edge-halves (partner lane: same dest, same cols)
        a0 += __shfl_xor(a0, 4); a1 += __shfl_xor(a1, 4);
        a2 += __shfl_xor(a2, 4); a3 += __shfl_xor(a3, 4);
        a4 += __shfl_xor(a4, 4); a5 += __shfl_xor(a5, 4);
        a6 += __shfl_xor(a6, 4); a7 += __shfl_xor(a7, 4);

        if (eh == 0) {
            const float bz = node_bias[dstu_k[dest]];
            bf8 o;
            o[0] = f2bf(tanhf(a0 + bz));
            o[1] = f2bf(tanhf(a1 + bz));
            o[2] = f2bf(tanhf(a2 + bz));
            o[3] = f2bf(tanhf(a3 + bz));
            o[4] = f2bf(tanhf(a4 + bz));
            o[5] = f2bf(tanhf(a5 + bz));
            o[6] = f2bf(tanhf(a6 + bz));
            o[7] = f2bf(tanhf(a7 + bz));
            *reinterpret_cast<bf8*>(curp + (size_t)dest * CCOLS + c8) = o;
        }
    }
}

// ---------------------------------------------------------------------------
// Step 7 fused with head stage 1 (unchanged from round 10; proven).
// ---------------------------------------------------------------------------
__global__ __launch_bounds__(256) void step7_head_k(const unsigned short* __restrict__ hprev,
                                                    const int*   __restrict__ src_k,
                                                    const float* __restrict__ w_k,
                                                    const float* __restrict__ node_bias,
                                                    const int*   __restrict__ dstu_k,
                                                    const float* __restrict__ head_W, // [LEVEL][2]
                                                    float*       __restrict__ part,
                                                    int src_base) {
    const int bid   = blockIdx.x;
    const int chunk = bid & 7;
    const int cb    = bid >> 3;                // 0..156
    const int tid   = threadIdx.x;

    __shared__ int   s_src[64 * MSTRIDE];
    __shared__ float s_w  [64 * MSTRIDE];
    __shared__ float o_tile[64][33];
    __shared__ float s_W2[64][2];
    __shared__ float red[8][64];

    {
        const int m4 = cb * 256 + tid;
        if (m4 < EPSZ / 4) {
            const int4   sv = reinterpret_cast<const int4*>(src_k)[m4];
            const float4 wv = reinterpret_cast<const float4*>(w_k)[m4];
            const int j = tid >> 2, i = (tid & 3) * 4;
            *reinterpret_cast<int4*>  (&s_src[j * MSTRIDE + i]) = sv;
            *reinterpret_cast<float4*>(&s_w  [j * MSTRIDE + i]) = wv;
        }
    }
    if (tid < 32) {
        const int f4 = cb * 32 + tid;          // float4 idx; head_W has 5000
        float4 wv = make_float4(0.f, 0.f, 0.f, 0.f);
        if (f4 < (LEVEL * 2) / 4) wv = reinterpret_cast<const float4*>(head_W)[f4];
        s_W2[tid * 2 + 0][0] = wv.x; s_W2[tid * 2 + 0][1] = wv.y;
        s_W2[tid * 2 + 1][0] = wv.z; s_W2[tid * 2 + 1][1] = wv.w;
    }
    __syncthreads();

    const int wave = tid >> 6, lane = tid & 63;
    const int q    = lane >> 2;
    const int c8   = (lane & 3) * 8;
    const int j    = wave * 16 + q;
    const int dest = cb * 64 + j;

    const unsigned short* prev = hprev + (size_t)chunk * LEVEL * CCOLS;

    float o0 = 0.f, o1 = 0.f, o2 = 0.f, o3 = 0.f, o4 = 0.f, o5 = 0.f, o6 = 0.f, o7 = 0.f;
    if (dest < LEVEL) {
        const int4   s0 = *reinterpret_cast<const int4*>  (&s_src[j * MSTRIDE + 0]);
        const int4   s1 = *reinterpret_cast<const int4*>  (&s_src[j * MSTRIDE + 4]);
        const int4   s2 = *reinterpret_cast<const int4*>  (&s_src[j * MSTRIDE + 8]);
        const int4   s3 = *reinterpret_cast<const int4*>  (&s_src[j * MSTRIDE + 12]);
        const float4 w0 = *reinterpret_cast<const float4*>(&s_w  [j * MSTRIDE + 0]);
        const float4 w1 = *reinterpret_cast<const float4*>(&s_w  [j * MSTRIDE + 4]);
        const float4 w2 = *reinterpret_cast<const float4*>(&s_w  [j * MSTRIDE + 8]);
        const float4 w3 = *reinterpret_cast<const float4*>(&s_w  [j * MSTRIDE + 12]);

        float a0 = 0.f, a1 = 0.f, a2 = 0.f, a3 = 0.f, a4 = 0.f, a5 = 0.f, a6 = 0.f, a7 = 0.f;
#define ACC(sv, wv) { const int idx = (sv) - src_base;                                      \
    const bf8 v = *reinterpret_cast<const bf8*>(prev + (size_t)idx * CCOLS + c8);           \
    a0 = fmaf(bf2f(v[0]), (wv), a0); a1 = fmaf(bf2f(v[1]), (wv), a1);                       \
    a2 = fmaf(bf2f(v[2]), (wv), a2); a3 = fmaf(bf2f(v[3]), (wv), a3);                       \
    a4 = fmaf(bf2f(v[4]), (wv), a4); a5 = fmaf(bf2f(v[5]), (wv), a5);                       \
    a6 = fmaf(bf2f(v[6]), (wv), a6); a7 = fmaf(bf2f(v[7]), (wv), a7); }
        ACC(s0.x, w0.x) ACC(s0.y, w0.y) ACC(s0.z, w0.z) ACC(s0.w, w0.w)
        ACC(s1.x, w1.x) ACC(s1.y, w1.y) ACC(s1.z, w1.z) ACC(s1.w, w1.w)
        ACC(s2.x, w2.x) ACC(s2.y, w2.y) ACC(s2.z, w2.z) ACC(s2.w, w2.w)
        ACC(s3.x, w3.x) ACC(s3.y, w3.y) ACC(s3.z, w3.z) ACC(s3.w, w3.w)
#undef ACC
        const float bz = node_bias[dstu_k[dest]];
        o0 = tanhf(a0 + bz); o1 = tanhf(a1 + bz); o2 = tanhf(a2 + bz); o3 = tanhf(a3 + bz);
        o4 = tanhf(a4 + bz); o5 = tanhf(a5 + bz); o6 = tanhf(a6 + bz); o7 = tanhf(a7 + bz);
    }
    o_tile[j][c8 + 0] = o0; o_tile[j][c8 + 1] = o1;
    o_tile[j][c8 + 2] = o2; o_tile[j][c8 + 3] = o3;
    o_tile[j][c8 + 4] = o4; o_tile[j][c8 + 5] = o5;
    o_tile[j][c8 + 6] = o6; o_tile[j][c8 + 7] = o7;
    __syncthreads();

    {
        const int col = tid & 31, slot = tid >> 5;
        float a0 = 0.f, a1 = 0.f;
#pragma unroll
        for (int e = 0; e < 8; ++e) {
            const int jj = slot * 8 + e;
            const float v = o_tile[jj][col];
            a0 = fmaf(v, s_W2[jj][0], a0);
            a1 = fmaf(v, s_W2[jj][1], a1);
        }
        red[slot][col * 2 + 0] = a0;
        red[slot][col * 2 + 1] = a1;
    }
    __syncthreads();
    if (tid < 64) {
        float s = 0.f;
#pragma unroll
        for (int p = 0; p < 8; ++p) s += red[p][tid];
        part[((size_t)chunk * SBLK + cb) * 64 + tid] = s;
    }
}

// ---------------------------------------------------------------------------
// Head final: out[chunk*64 + t] = head_b[t&1] + sum_q part[(chunk*157+q)*64+t]
// ---------------------------------------------------------------------------
__global__ __launch_bounds__(64) void head_final_k(const float* __restrict__ part,
                                                   const float* __restrict__ head_b,
                                                   float*       __restrict__ out) {
    const int chunk = blockIdx.x;              // 8
    const int t     = threadIdx.x;             // 64
    float acc = head_b[t & 1];
    for (int q = 0; q < SBLK; ++q)
        acc += part[((size_t)chunk * SBLK + q) * 64 + t];
    out[chunk * 64 + t] = acc;
}

// ---------------------------------------------------------------------------
extern "C" void kernel_launch(void* const* d_in, const int* in_sizes, int n_in,
                              void* d_out, int out_size, void* d_ws, size_t ws_size,
                              hipStream_t stream) {
    const float* X           = (const float*)d_in[0];
    const float* edge_weight = (const float*)d_in[1];
    const float* node_bias   = (const float*)d_in[2];
    const float* head_W      = (const float*)d_in[3];
    const float* head_b      = (const float*)d_in[4];
    const int*   gene_map    = (const int*)  d_in[5];
    const int*   src         = (const int*)  d_in[6];
    /* d_in[7] = dst_pos: structurally repeat(arange(LEVEL),DEG) — encoded in layout */
    const int*   dst_unique  = (const int*)  d_in[8];
    /* d_in[9] = eid: structurally arange(E).reshape(STEPS,EPS) — weights contiguous */
    /* d_in[10] = root_ids: structurally dst_unique[-1] — head fused into step 7 */
    float* out = (float*)d_out;

    // workspace layout (bytes)
    char* ws = (char*)d_ws;
    unsigned short* XT   = (unsigned short*)(ws);              // 8*20000*32*2 = 10,240,000
    unsigned short* lvlA = (unsigned short*)(ws + 10240000);   // 8*10000*32*2 =  5,120,000
    unsigned short* lvlB = (unsigned short*)(ws + 15360000);   //                 5,120,000
    float*          part = (float*)         (ws + 20480000);   // 8*157*64*4   =    321,536

    // 1) transpose X into chunked bf16 node-major planes (chunk -> XCD pinned)
    transpose_k<<<dim3(NCHUNK, 157), 256, 0, stream>>>(X, gene_map, XT);

    // 2) levels 1..6, ping-pong level buffers, chunk -> XCD pinned
    unsigned short* bufs[2] = {lvlA, lvlB};
    for (int k = 0; k < STEPS - 1; ++k) {
        const unsigned short* hprev = (k == 0) ? XT : bufs[(k - 1) & 1];
        const int prevrows = (k == 0) ? GENES : LEVEL;
        const int srcbase  = (k == 0) ? 0 : GENES + (k - 1) * LEVEL;
        step_k<<<DBLK * NCHUNK, 256, 0, stream>>>(hprev, bufs[k & 1],
                                                  src + (size_t)k * EPSZ,
                                                  edge_weight + (size_t)k * EPSZ,
                                                  node_bias,
                                                  dst_unique + (size_t)k * LEVEL,
                                                  srcbase, prevrows);
    }

    // 3) level 7 fused with head partials (no plane store), then tiny final
    {
        const int k = STEPS - 1;                            // 6
        const unsigned short* hprev = bufs[(k - 1) & 1];    // lvlB
        const int srcbase = GENES + (k - 1) * LEVEL;
        step7_head_k<<<SBLK * NCHUNK, 256, 0, stream>>>(hprev,
                                                        src + (size_t)k * EPSZ,
                                                        edge_weight + (size_t)k * EPSZ,
                                                        node_bias,
                                                        dst_unique + (size_t)k * LEVEL,
                                                        head_W, part, srcbase);
        head_final_k<<<NCHUNK, 64, 0, stream>>>(part, head_b, out);
    }
    (void)in_sizes; (void)n_in; (void)out_size; (void)ws_size;
}